// Round 6
// baseline (140.110 us; speedup 1.0000x reference)
//
#include <hip/hip_runtime.h>

#define NB 8192
#define SS 32
#define NEDGE 131072
#define GPB 16                      // graphs per block
#define ITERS (GPB / 2)             // 2 graphs per iteration
#define EB 128                      // edge partial blocks
#define EPB (NEDGE / EB)            // 1024 edges per block
#define ATT_SCALE 0.35355339059327373f
#define LN_EPS 1e-5f

typedef const float* __restrict__ cfp;
typedef __attribute__((ext_vector_type(8))) short bfrag;   // 8 bf16
typedef __attribute__((ext_vector_type(4))) float f32x4;

__device__ inline short f2bf(float f) {                    // RNE f32 -> bf16
  union { float f; unsigned u; } un; un.f = f;
  unsigned r = un.u + 0x7FFFu + ((un.u >> 16) & 1u);
  return (short)(r >> 16);
}
__device__ inline float bf2f(short s) {
  union { unsigned u; float f; } un;
  un.u = ((unsigned)(unsigned short)s) << 16;
  return un.f;
}
__device__ inline unsigned cvt_pk(float lo, float hi) {    // 2xf32 -> bf16x2
  unsigned r;
  asm("v_cvt_pk_bf16_f32 %0, %1, %2" : "=v"(r) : "v"(lo), "v"(hi));
  return r;
}
// swizzled LDS address (shorts): 16B groups XOR'd by row&7
__device__ inline int lad(int row, int col) {
  return row * 64 + (((col >> 3) ^ (row & 7)) * 8) + (col & 7);
}

// ------------- Kernel 1a: edge weights -> per-block partial W in LDS --------
__global__ __launch_bounds__(256) void edge_partial_kernel(
    cfp edge_attr, const int* __restrict__ edge_index, cfp we, cfp be,
    float* __restrict__ Wpart) {
  __shared__ float Wl[8 * SS * SS];    // 32 KB private W accumulator
  __shared__ float ea[64][68];
  __shared__ float wes[64][8];
  __shared__ float bes[8];
  const int t = threadIdx.x;
  for (int i = t; i < 8 * SS * SS; i += 256) Wl[i] = 0.f;
  if (t < 128) ((float4*)wes)[t] = ((const float4*)we)[t];
  if (t < 8) bes[t] = be[t];
  __syncthreads();

  for (int tile = 0; tile < EPB / 64; ++tile) {
    const long ebase = (long)blockIdx.x * EPB + tile * 64;
    const float4* src4 = (const float4*)(edge_attr + ebase * 64);
#pragma unroll
    for (int q = 0; q < 4; ++q) {
      int slot = q * 256 + t;
      int eL = slot >> 4, c4 = (slot & 15) * 4;
      float4 v = src4[slot];
      *(float4*)&ea[eL][c4] = v;
    }
    __syncthreads();
    const int eL = t >> 2;
    const int h0 = (t & 3) * 2;
    float d0 = 0.f, d1 = 0.f;
#pragma unroll
    for (int k = 0; k < 64; ++k) {
      float a = ea[eL][k];
      d0 += a * wes[k][h0];
      d1 += a * wes[k][h0 + 1];
    }
    const long eG = ebase + eL;
    const int s = edge_index[eG];
    const int d = edge_index[NEDGE + eG];
    atomicAdd(&Wl[(h0 * SS + s) * SS + d], d0 + bes[h0]);
    atomicAdd(&Wl[((h0 + 1) * SS + s) * SS + d], d1 + bes[h0 + 1]);
    __syncthreads();
  }
  const float4* Wl4 = (const float4*)Wl;
  float4* dst = (float4*)(Wpart + (long)blockIdx.x * 8192);
  for (int i = t; i < 2048; i += 256) dst[i] = Wl4[i];
}

// ------------- Kernel 1b: parallel reduce partials -> W ---------------------
// 32 blocks x 256 thr: 64 float4 slots/block, 4 groups each sum 32 partials.
__global__ __launch_bounds__(256) void edge_reduce_kernel(
    cfp Wpart, float* __restrict__ W) {
  __shared__ float4 accs[4][64];
  const int t = threadIdx.x;
  const int slot = blockIdx.x * 64 + (t & 63);    // float4 slot in [0,2048)
  const int grp = t >> 6;
  float4 s = make_float4(0.f, 0.f, 0.f, 0.f);
#pragma unroll 4
  for (int p = grp * (EB / 4); p < (grp + 1) * (EB / 4); ++p) {
    float4 v = ((const float4*)Wpart)[(long)p * 2048 + slot];
    s.x += v.x; s.y += v.y; s.z += v.z; s.w += v.w;
  }
  accs[grp][t & 63] = s;
  __syncthreads();
  if (t < 64) {
    float4 a = accs[0][t], b = accs[1][t], c = accs[2][t], d = accs[3][t];
    float4 r;
    r.x = (a.x + b.x) + (c.x + d.x);
    r.y = (a.y + b.y) + (c.y + d.y);
    r.z = (a.z + b.z) + (c.z + d.z);
    r.w = (a.w + b.w) + (c.w + d.w);
    ((float4*)W)[blockIdx.x * 64 + t] = r;
  }
}

// ------------- Kernel 2: fused encoder (R3 structure, tanh GELU) ------------
__global__ __launch_bounds__(512, 4) void encoder_kernel(
    cfp x, const int* __restrict__ batch,
    cfp wq, cfp bq, cfp wk, cfp bk, cfp wv, cfp bv, cfp wo, cfp bo,
    cfp ln1g, cfp ln1b, cfp ln2g, cfp ln2b,
    cfp w1, cfp bf1, cfp w2, cfp bf2,
    cfp W, float* __restrict__ out) {

  __shared__ short wt[6][64 * 64];      // wt[m][lad(n,k)] = bf16(w[k][n])
  __shared__ short P[64 * 64], Q[64 * 64], R[64 * 64];
  __shared__ float bias_s[10][64];      // bq bk bv bo b1 b2 ln1g ln1b ln2g ln2b
  __shared__ int batch_s[SS];

  const int t = threadIdx.x;

  // ---- one-time staging ----
  {
    const int n = t & 63, kb = (t >> 6) * 8;
    auto stage = [&](cfp src, short* dst) {
      bfrag p;
#pragma unroll
      for (int j = 0; j < 8; ++j) p[j] = f2bf(src[(kb + j) * 64 + n]);
      *(bfrag*)&dst[lad(n, kb)] = p;
    };
    stage(wq, wt[0]); stage(wk, wt[1]); stage(wv, wt[2]);
    stage(wo, wt[3]); stage(w1, wt[4]); stage(w2, wt[5]);
  }
  if (t < 64) {
    bias_s[0][t] = bq[t];   bias_s[1][t] = bk[t];   bias_s[2][t] = bv[t];
    bias_s[3][t] = bo[t];   bias_s[4][t] = bf1[t];  bias_s[5][t] = bf2[t];
    bias_s[6][t] = ln1g[t]; bias_s[7][t] = ln1b[t];
    bias_s[8][t] = ln2g[t]; bias_s[9][t] = ln2b[t];
  }
  if (t < SS) batch_s[t] = batch[t];
  __syncthreads();

  const int lane = t & 63, w = t >> 6;
  const int g = lane >> 4, r = lane & 15;     // MFMA fragment coords
  const int tr = w >> 1, tc0 = (w & 1) * 2;   // GEMM: M-tile, N-tile pair
  const int s8 = t >> 3, c8 = (t & 7) * 8;    // LN mapping (64 rows x 8 thr)
  const int gW = w >> 2, hb = (w & 3) * 2;    // attn: wave graph + head pair
  const f32x4 zero4 = {0.f, 0.f, 0.f, 0.f};

  auto mm2 = [&](const short* A, const short* Wm, f32x4 acc[2]) {
    const int rr = tr * 16 + r;
    bfrag a0 = *(const bfrag*)&A[lad(rr, g * 8)];
    bfrag a1 = *(const bfrag*)&A[lad(rr, 32 + g * 8)];
#pragma unroll
    for (int i = 0; i < 2; ++i) {
      const int n = (tc0 + i) * 16 + r;
      bfrag b0 = *(const bfrag*)&Wm[lad(n, g * 8)];
      bfrag b1 = *(const bfrag*)&Wm[lad(n, 32 + g * 8)];
      acc[i] = __builtin_amdgcn_mfma_f32_16x16x32_bf16(a0, b0, acc[i], 0, 0, 0);
      acc[i] = __builtin_amdgcn_mfma_f32_16x16x32_bf16(a1, b1, acc[i], 0, 0, 0);
    }
  };

  for (int it = 0; it < ITERS; ++it) {
    const int giter = blockIdx.x * GPB + it * 2;   // first of 2 graphs

    // ---- ph1: LN1(x) -> P (bf16) ----
    {
      float xv[8];
      const float4* px = (const float4*)(x + ((long)(giter * 32 + s8)) * 64 + c8);
      float4 a = px[0], c = px[1];
      xv[0]=a.x; xv[1]=a.y; xv[2]=a.z; xv[3]=a.w;
      xv[4]=c.x; xv[5]=c.y; xv[6]=c.z; xv[7]=c.w;
      float sum = 0.f;
#pragma unroll
      for (int i = 0; i < 8; ++i) sum += xv[i];
      sum += __shfl_xor(sum, 1); sum += __shfl_xor(sum, 2); sum += __shfl_xor(sum, 4);
      const float m = sum * (1.f / 64.f);
      float sq = 0.f;
#pragma unroll
      for (int i = 0; i < 8; ++i) { float dd = xv[i] - m; sq += dd * dd; }
      sq += __shfl_xor(sq, 1); sq += __shfl_xor(sq, 2); sq += __shfl_xor(sq, 4);
      const float rs = rsqrtf(sq * (1.f / 64.f) + LN_EPS);
      bfrag yv;
#pragma unroll
      for (int i = 0; i < 8; ++i)
        yv[i] = f2bf((xv[i] - m) * rs * bias_s[6][c8 + i] + bias_s[7][c8 + i]);
      *(bfrag*)&P[lad(s8, c8)] = yv;
    }
    __syncthreads();                                       // bar A

    // ---- ph2: QKV projections; q*SCALE -> Q, k -> R, v -> P as V^T ----
    {
      const int rr = tr * 16 + r;
      bfrag a0 = *(const bfrag*)&P[lad(rr, g * 8)];
      bfrag a1 = *(const bfrag*)&P[lad(rr, 32 + g * 8)];
      f32x4 acc[3][2];
#pragma unroll
      for (int m = 0; m < 3; ++m) { acc[m][0] = zero4; acc[m][1] = zero4; }
#pragma unroll
      for (int i = 0; i < 2; ++i) {
        const int n = (tc0 + i) * 16 + r;
#pragma unroll
        for (int m = 0; m < 3; ++m) {
          bfrag b0 = *(const bfrag*)&wt[m][lad(n, g * 8)];
          bfrag b1 = *(const bfrag*)&wt[m][lad(n, 32 + g * 8)];
          acc[m][i] = __builtin_amdgcn_mfma_f32_16x16x32_bf16(a0, b0, acc[m][i], 0, 0, 0);
          acc[m][i] = __builtin_amdgcn_mfma_f32_16x16x32_bf16(a1, b1, acc[m][i], 0, 0, 0);
        }
      }
#pragma unroll
      for (int i = 0; i < 2; ++i) {
        const int col = (tc0 + i) * 16 + r;
        const float bq_ = bias_s[0][col], bk_ = bias_s[1][col];
#pragma unroll
        for (int j = 0; j < 4; ++j) {
          const int row = tr * 16 + g * 4 + j;
          const int ad = lad(row, col);
          Q[ad] = f2bf((acc[0][i][j] + bq_) * ATT_SCALE);
          R[ad] = f2bf(acc[1][i][j] + bk_);
        }
      }
      __syncthreads();                                     // bar B (P reads done)
#pragma unroll
      for (int i = 0; i < 2; ++i) {
        const int hd = (tc0 + i) * 16 + r;
        const float bv_ = bias_s[2][hd];
        const int graph = tr >> 1;
        const int tgrp = (tr & 1) * 2 + (g >> 1);
        unsigned p0 = cvt_pk(acc[2][i][0] + bv_, acc[2][i][1] + bv_);
        unsigned p1 = cvt_pk(acc[2][i][2] + bv_, acc[2][i][3] + bv_);
        const int ad = graph * 2048 + hd * 32 + ((tgrp ^ (hd & 3)) * 8) + (g & 1) * 4;
        *(unsigned*)&P[ad] = p0;
        *(unsigned*)&P[ad + 2] = p1;
      }
    }
    __syncthreads();                                       // bar C

    // ---- ph3: attention on MFMA (S^T = K Q^T; softmax lane-local; PV) ----
    {
      const int gidx2 = giter + gW;
#pragma unroll
      for (int u = 0; u < 2; ++u) {
        const int h = hb + u;
        bfrag kf0 = {0,0,0,0,0,0,0,0}, kf1 = kf0;
        if (g == 0) {
          kf0 = *(const bfrag*)&R[lad(gW * 32 + r, h * 8)];
          kf1 = *(const bfrag*)&R[lad(gW * 32 + 16 + r, h * 8)];
        }
#pragma unroll
        for (int st = 0; st < 2; ++st) {
          const int sL = st * 16 + r;
          bfrag qf = {0,0,0,0,0,0,0,0};
          if (g == 0) qf = *(const bfrag*)&Q[lad(gW * 32 + sL, h * 8)];
          f32x4 sc0 = zero4, sc1 = zero4;
          sc0 = __builtin_amdgcn_mfma_f32_16x16x32_bf16(kf0, qf, sc0, 0, 0, 0);
          sc1 = __builtin_amdgcn_mfma_f32_16x16x32_bf16(kf1, qf, sc1, 0, 0, 0);
          f32x4 wb0 = zero4, wb1 = zero4;
          if (batch_s[sL] == gidx2) {
            wb0 = *(const f32x4*)&W[(h * 32 + sL) * 32 + 4 * g];
            wb1 = *(const f32x4*)&W[(h * 32 + sL) * 32 + 16 + 4 * g];
          }
          float v0[4], v1[4];
#pragma unroll
          for (int j = 0; j < 4; ++j) { v0[j] = sc0[j] + wb0[j]; v1[j] = sc1[j] + wb1[j]; }
          float mx = fmaxf(fmaxf(fmaxf(v0[0], v0[1]), fmaxf(v0[2], v0[3])),
                           fmaxf(fmaxf(v1[0], v1[1]), fmaxf(v1[2], v1[3])));
          mx = fmaxf(mx, __shfl_xor(mx, 16));
          mx = fmaxf(mx, __shfl_xor(mx, 32));
          float e0[4], e1[4], ssum = 0.f;
#pragma unroll
          for (int j = 0; j < 4; ++j) {
            e0[j] = __expf(v0[j] - mx); e1[j] = __expf(v1[j] - mx);
            ssum += e0[j] + e1[j];
          }
          ssum += __shfl_xor(ssum, 16);
          ssum += __shfl_xor(ssum, 32);
          const float inv = __builtin_amdgcn_rcpf(ssum);
          unsigned u0 = cvt_pk(e0[0], e0[1]), u1 = cvt_pk(e0[2], e0[3]);
          unsigned u2 = cvt_pk(e1[0], e1[1]), u3 = cvt_pk(e1[2], e1[3]);
          const int srcA = ((g & 1) * 2) * 16 + r, srcB = srcA + 16;
          unsigned A0 = (unsigned)__shfl((int)u0, srcA);
          unsigned A2 = (unsigned)__shfl((int)u2, srcA);
          unsigned B0 = (unsigned)__shfl((int)u1, srcA);
          unsigned B2 = (unsigned)__shfl((int)u3, srcA);
          unsigned C0 = (unsigned)__shfl((int)u0, srcB);
          unsigned C2 = (unsigned)__shfl((int)u2, srcB);
          unsigned D0 = (unsigned)__shfl((int)u1, srcB);
          unsigned D2 = (unsigned)__shfl((int)u3, srcB);
          const bool hi = (g >> 1);
          uint4 bw;
          bw.x = hi ? A2 : A0;
          bw.y = hi ? B2 : B0;
          bw.z = hi ? C2 : C0;
          bw.w = hi ? D2 : D0;
          bfrag pb = *(bfrag*)&bw;
          bfrag vf = {0,0,0,0,0,0,0,0};
          if (r < 8) {
            const int hd = h * 8 + r;
            vf = *(const bfrag*)&P[gW * 2048 + hd * 32 + ((g ^ (hd & 3)) * 8)];
          }
          f32x4 o = zero4;
          o = __builtin_amdgcn_mfma_f32_16x16x32_bf16(vf, pb, o, 0, 0, 0);
          if (g < 2) {
            unsigned w0 = cvt_pk(o[0] * inv, o[1] * inv);
            unsigned w1 = cvt_pk(o[2] * inv, o[3] * inv);
            const int row = gW * 32 + sL;
            const int ad = lad(row, h * 8) + g * 4;
            *(unsigned*)&Q[ad] = w0;
            *(unsigned*)&Q[ad + 2] = w1;
          }
        }
      }
    }
    __syncthreads();                                       // bar D

    // ---- ph4: out-proj + residual; x1 -> R (bf16) + rx regs (f32) ----
    f32x4 rx[2];
    {
      f32x4 acc[2] = {zero4, zero4};
      mm2(Q, wt[3], acc);
#pragma unroll
      for (int i = 0; i < 2; ++i) {
        const int col = (tc0 + i) * 16 + r;
        const float bb = bias_s[3][col];
#pragma unroll
        for (int j = 0; j < 4; ++j) {
          const int row = tr * 16 + g * 4 + j;
          const float xv = x[((long)(giter * 32 + row)) * 64 + col];
          const float v = acc[i][j] + bb + xv;
          rx[i][j] = v;
          R[lad(row, col)] = f2bf(v);
        }
      }
    }
    __syncthreads();                                       // bar E

    // ---- ph5: LN2(x1) -> P ----
    {
      bfrag xv8 = *(const bfrag*)&R[lad(s8, c8)];
      float zv[8];
#pragma unroll
      for (int i = 0; i < 8; ++i) zv[i] = bf2f(xv8[i]);
      float sum = 0.f;
#pragma unroll
      for (int i = 0; i < 8; ++i) sum += zv[i];
      sum += __shfl_xor(sum, 1); sum += __shfl_xor(sum, 2); sum += __shfl_xor(sum, 4);
      const float m = sum * (1.f / 64.f);
      float sq = 0.f;
#pragma unroll
      for (int i = 0; i < 8; ++i) { float dd = zv[i] - m; sq += dd * dd; }
      sq += __shfl_xor(sq, 1); sq += __shfl_xor(sq, 2); sq += __shfl_xor(sq, 4);
      const float rs = rsqrtf(sq * (1.f / 64.f) + LN_EPS);
      bfrag zb;
#pragma unroll
      for (int i = 0; i < 8; ++i)
        zb[i] = f2bf((zv[i] - m) * rs * bias_s[8][c8 + i] + bias_s[9][c8 + i]);
      *(bfrag*)&P[lad(s8, c8)] = zb;
    }
    __syncthreads();                                       // bar F

    // ---- ph6: FFN1 + tanh-form GELU -> Q ----
    {
      f32x4 acc[2] = {zero4, zero4};
      mm2(P, wt[4], acc);
#pragma unroll
      for (int i = 0; i < 2; ++i) {
        const int col = (tc0 + i) * 16 + r;
        const float bb = bias_s[4][col];
#pragma unroll
        for (int j = 0; j < 4; ++j) {
          const int row = tr * 16 + g * 4 + j;
          const float u_ = acc[i][j] + bb;
          const float z = -1.5957691216f * (u_ + 0.044715f * u_ * u_ * u_);
          Q[lad(row, col)] = f2bf(u_ * __builtin_amdgcn_rcpf(1.f + __expf(z)));
        }
      }
    }
    __syncthreads();                                       // bar G

    // ---- ph7: FFN2 + residual -> out ----
    {
      f32x4 acc[2] = {zero4, zero4};
      mm2(Q, wt[5], acc);
#pragma unroll
      for (int i = 0; i < 2; ++i) {
        const int col = (tc0 + i) * 16 + r;
        const float bb = bias_s[5][col];
#pragma unroll
        for (int j = 0; j < 4; ++j) {
          const int row = tr * 16 + g * 4 + j;
          out[((long)(giter * 32 + row)) * 64 + col] = acc[i][j] + bb + rx[i][j];
        }
      }
    }
  }
}

extern "C" void kernel_launch(void* const* d_in, const int* in_sizes, int n_in,
                              void* d_out, int out_size, void* d_ws, size_t ws_size,
                              hipStream_t stream) {
  (void)in_sizes; (void)n_in; (void)out_size; (void)ws_size;
  cfp x         = (cfp)d_in[0];
  cfp edge_attr = (cfp)d_in[1];
  const int* edge_index = (const int*)d_in[2];
  const int* batch      = (const int*)d_in[3];
  cfp wq = (cfp)d_in[4];  cfp bq = (cfp)d_in[5];
  cfp wk = (cfp)d_in[6];  cfp bk = (cfp)d_in[7];
  cfp wv = (cfp)d_in[8];  cfp bv = (cfp)d_in[9];
  cfp we = (cfp)d_in[10]; cfp be = (cfp)d_in[11];
  cfp wo = (cfp)d_in[12]; cfp bo = (cfp)d_in[13];
  cfp ln1g = (cfp)d_in[14]; cfp ln1b = (cfp)d_in[15];
  cfp ln2g = (cfp)d_in[16]; cfp ln2b = (cfp)d_in[17];
  cfp w1 = (cfp)d_in[18]; cfp bf1 = (cfp)d_in[19];
  cfp w2 = (cfp)d_in[20]; cfp bf2 = (cfp)d_in[21];
  float* out = (float*)d_out;
  float* W = (float*)d_ws;        // NH*S*S floats = 32 KB
  float* Wpart = (float*)d_out;   // scratch: 4 MB of d_out, fully overwritten
                                  // later by the encoder's out writes

  edge_partial_kernel<<<EB, 256, 0, stream>>>(edge_attr, edge_index, we, be, Wpart);
  edge_reduce_kernel<<<32, 256, 0, stream>>>(Wpart, W);
  encoder_kernel<<<NB / GPB, 512, 0, stream>>>(x, batch,
      wq, bq, wk, bk, wv, bv, wo, bo,
      ln1g, ln1b, ln2g, ln2b, w1, bf1, w2, bf2, W, out);
}

// Round 7
// 96.843 us; speedup vs baseline: 1.4468x; 1.4468x over previous
//
#include <hip/hip_runtime.h>

#define NB 8192
#define SS 32
#define NEDGE 131072
#define GPB 16                      // graphs per block
#define ITERS (GPB / 2)             // 2 graphs per iteration
#define EB 256                      // edge partial blocks
#define EPB (NEDGE / EB)            // 512 edges per block
#define ATT_SCALE 0.35355339059327373f
#define LN_EPS 1e-5f

typedef const float* __restrict__ cfp;
typedef __attribute__((ext_vector_type(8))) short bfrag;   // 8 bf16
typedef __attribute__((ext_vector_type(4))) float f32x4;

__device__ inline short f2bf(float f) {                    // RNE f32 -> bf16
  union { float f; unsigned u; } un; un.f = f;
  unsigned r = un.u + 0x7FFFu + ((un.u >> 16) & 1u);
  return (short)(r >> 16);
}
__device__ inline float bf2f(short s) {
  union { unsigned u; float f; } un;
  un.u = ((unsigned)(unsigned short)s) << 16;
  return un.f;
}
__device__ inline unsigned cvt_pk(float lo, float hi) {    // 2xf32 -> bf16x2
  unsigned r;
  asm("v_cvt_pk_bf16_f32 %0, %1, %2" : "=v"(r) : "v"(lo), "v"(hi));
  return r;
}
__device__ inline bfrag pack8(const float* y) {            // 8 f32 -> bfrag
  union { uint4 u4; bfrag b; } c;
  c.u4.x = cvt_pk(y[0], y[1]); c.u4.y = cvt_pk(y[2], y[3]);
  c.u4.z = cvt_pk(y[4], y[5]); c.u4.w = cvt_pk(y[6], y[7]);
  return c.b;
}
// swizzled LDS address (shorts): 16B groups XOR'd by row&7
__device__ inline int lad(int row, int col) {
  return row * 64 + (((col >> 3) ^ (row & 7)) * 8) + (col & 7);
}

// ------------- Kernel 1a: edge GEMM on MFMA -> per-block partial W ----------
// 16 edges/wave: A = bf16(edge_attr rows) from global, B = we frags in regs,
// C[edge][head] scattered into LDS Wl via edge_index. No barriers in loop.
__global__ __launch_bounds__(256) void edge_partial_kernel(
    cfp edge_attr, const int* __restrict__ edge_index, cfp we, cfp be,
    float* __restrict__ Wpart) {
  __shared__ float Wl[8 * SS * SS];    // 32 KB private W accumulator
  const int t = threadIdx.x;
  const int lane = t & 63, w = t >> 6;
  const int g = lane >> 4, r = lane & 15;
  for (int i = t; i < 8 * SS * SS; i += 256) Wl[i] = 0.f;

  // B-frags: lane (g,r) holds we[k=g*8..+8][col=r] (cols 8..15 zero-padded)
  bfrag b0 = {0,0,0,0,0,0,0,0}, b1 = b0;
  float beh = 0.f;
  if (r < 8) {
#pragma unroll
    for (int j = 0; j < 8; ++j) {
      b0[j] = f2bf(we[(g * 8 + j) * 8 + r]);
      b1[j] = f2bf(we[(32 + g * 8 + j) * 8 + r]);
    }
    beh = be[r];
  }
  __syncthreads();

  const f32x4 zero4 = {0.f, 0.f, 0.f, 0.f};
  for (int itr = 0; itr < EPB / 64; ++itr) {
    const int e0 = blockIdx.x * EPB + itr * 64 + w * 16;
    const float* src = edge_attr + (long)(e0 + r) * 64;   // A row = edge e0+r
    float va[8], vb[8];
    *(float4*)&va[0] = *(const float4*)(src + g * 8);
    *(float4*)&va[4] = *(const float4*)(src + g * 8 + 4);
    *(float4*)&vb[0] = *(const float4*)(src + 32 + g * 8);
    *(float4*)&vb[4] = *(const float4*)(src + 32 + g * 8 + 4);
    bfrag a0 = pack8(va), a1 = pack8(vb);
    f32x4 c = zero4;
    c = __builtin_amdgcn_mfma_f32_16x16x32_bf16(a0, b0, c, 0, 0, 0);
    c = __builtin_amdgcn_mfma_f32_16x16x32_bf16(a1, b1, c, 0, 0, 0);
    // C: col(head)=lane&15, row(edge)=g*4+j
    if (r < 8) {
#pragma unroll
      for (int j = 0; j < 4; ++j) {
        const int eg = e0 + g * 4 + j;
        const int s = edge_index[eg];
        const int d = edge_index[NEDGE + eg];
        atomicAdd(&Wl[(r * SS + s) * SS + d], c[j] + beh);
      }
    }
  }
  __syncthreads();
  const float4* Wl4 = (const float4*)Wl;
  float4* dst = (float4*)(Wpart + (long)blockIdx.x * 8192);
  for (int i = t; i < 2048; i += 256) dst[i] = Wl4[i];
}

// ------------- Kernel 1b: parallel reduce partials -> W ---------------------
// 64 blocks x 256 thr: 32 float4 slots/block, 8 groups each sum 32 partials.
__global__ __launch_bounds__(256) void edge_reduce_kernel(
    cfp Wpart, float* __restrict__ W) {
  __shared__ float4 accs[8][32];
  const int t = threadIdx.x;
  const int slot = blockIdx.x * 32 + (t & 31);    // float4 slot in [0,2048)
  const int grp = t >> 5;
  float4 s = make_float4(0.f, 0.f, 0.f, 0.f);
#pragma unroll 4
  for (int p = grp * 32; p < grp * 32 + 32; ++p) {
    float4 v = ((const float4*)Wpart)[(long)p * 2048 + slot];
    s.x += v.x; s.y += v.y; s.z += v.z; s.w += v.w;
  }
  accs[grp][t & 31] = s;
  __syncthreads();
  if (t < 32) {
    float4 a = accs[0][t];
#pragma unroll
    for (int q = 1; q < 8; ++q) {
      float4 v = accs[q][t];
      a.x += v.x; a.y += v.y; a.z += v.z; a.w += v.w;
    }
    ((float4*)W)[blockIdx.x * 32 + t] = a;
  }
}

// ------------- Kernel 2: fused encoder (R6 structure, unchanged) ------------
__global__ __launch_bounds__(512, 4) void encoder_kernel(
    cfp x, const int* __restrict__ batch,
    cfp wq, cfp bq, cfp wk, cfp bk, cfp wv, cfp bv, cfp wo, cfp bo,
    cfp ln1g, cfp ln1b, cfp ln2g, cfp ln2b,
    cfp w1, cfp bf1, cfp w2, cfp bf2,
    cfp W, float* __restrict__ out) {

  __shared__ short wt[6][64 * 64];      // wt[m][lad(n,k)] = bf16(w[k][n])
  __shared__ short P[64 * 64], Q[64 * 64], R[64 * 64];
  __shared__ float bias_s[10][64];      // bq bk bv bo b1 b2 ln1g ln1b ln2g ln2b
  __shared__ int batch_s[SS];

  const int t = threadIdx.x;

  // ---- one-time staging ----
  {
    const int n = t & 63, kb = (t >> 6) * 8;
    auto stage = [&](cfp src, short* dst) {
      bfrag p;
#pragma unroll
      for (int j = 0; j < 8; ++j) p[j] = f2bf(src[(kb + j) * 64 + n]);
      *(bfrag*)&dst[lad(n, kb)] = p;
    };
    stage(wq, wt[0]); stage(wk, wt[1]); stage(wv, wt[2]);
    stage(wo, wt[3]); stage(w1, wt[4]); stage(w2, wt[5]);
  }
  if (t < 64) {
    bias_s[0][t] = bq[t];   bias_s[1][t] = bk[t];   bias_s[2][t] = bv[t];
    bias_s[3][t] = bo[t];   bias_s[4][t] = bf1[t];  bias_s[5][t] = bf2[t];
    bias_s[6][t] = ln1g[t]; bias_s[7][t] = ln1b[t];
    bias_s[8][t] = ln2g[t]; bias_s[9][t] = ln2b[t];
  }
  if (t < SS) batch_s[t] = batch[t];
  __syncthreads();

  const int lane = t & 63, w = t >> 6;
  const int g = lane >> 4, r = lane & 15;     // MFMA fragment coords
  const int tr = w >> 1, tc0 = (w & 1) * 2;   // GEMM: M-tile, N-tile pair
  const int s8 = t >> 3, c8 = (t & 7) * 8;    // LN mapping (64 rows x 8 thr)
  const int gW = w >> 2, hb = (w & 3) * 2;    // attn: wave graph + head pair
  const f32x4 zero4 = {0.f, 0.f, 0.f, 0.f};

  auto mm2 = [&](const short* A, const short* Wm, f32x4 acc[2]) {
    const int rr = tr * 16 + r;
    bfrag a0 = *(const bfrag*)&A[lad(rr, g * 8)];
    bfrag a1 = *(const bfrag*)&A[lad(rr, 32 + g * 8)];
#pragma unroll
    for (int i = 0; i < 2; ++i) {
      const int n = (tc0 + i) * 16 + r;
      bfrag b0 = *(const bfrag*)&Wm[lad(n, g * 8)];
      bfrag b1 = *(const bfrag*)&Wm[lad(n, 32 + g * 8)];
      acc[i] = __builtin_amdgcn_mfma_f32_16x16x32_bf16(a0, b0, acc[i], 0, 0, 0);
      acc[i] = __builtin_amdgcn_mfma_f32_16x16x32_bf16(a1, b1, acc[i], 0, 0, 0);
    }
  };

  for (int it = 0; it < ITERS; ++it) {
    const int giter = blockIdx.x * GPB + it * 2;   // first of 2 graphs

    // ---- ph1: LN1(x) -> P (bf16) ----
    {
      float xv[8];
      const float4* px = (const float4*)(x + ((long)(giter * 32 + s8)) * 64 + c8);
      float4 a = px[0], c = px[1];
      xv[0]=a.x; xv[1]=a.y; xv[2]=a.z; xv[3]=a.w;
      xv[4]=c.x; xv[5]=c.y; xv[6]=c.z; xv[7]=c.w;
      float sum = 0.f;
#pragma unroll
      for (int i = 0; i < 8; ++i) sum += xv[i];
      sum += __shfl_xor(sum, 1); sum += __shfl_xor(sum, 2); sum += __shfl_xor(sum, 4);
      const float m = sum * (1.f / 64.f);
      float sq = 0.f;
#pragma unroll
      for (int i = 0; i < 8; ++i) { float dd = xv[i] - m; sq += dd * dd; }
      sq += __shfl_xor(sq, 1); sq += __shfl_xor(sq, 2); sq += __shfl_xor(sq, 4);
      const float rs = rsqrtf(sq * (1.f / 64.f) + LN_EPS);
      bfrag yv;
#pragma unroll
      for (int i = 0; i < 8; ++i)
        yv[i] = f2bf((xv[i] - m) * rs * bias_s[6][c8 + i] + bias_s[7][c8 + i]);
      *(bfrag*)&P[lad(s8, c8)] = yv;
    }
    __syncthreads();                                       // bar A

    // ---- ph2: QKV projections; q*SCALE -> Q, k -> R, v -> P as V^T ----
    {
      const int rr = tr * 16 + r;
      bfrag a0 = *(const bfrag*)&P[lad(rr, g * 8)];
      bfrag a1 = *(const bfrag*)&P[lad(rr, 32 + g * 8)];
      f32x4 acc[3][2];
#pragma unroll
      for (int m = 0; m < 3; ++m) { acc[m][0] = zero4; acc[m][1] = zero4; }
#pragma unroll
      for (int i = 0; i < 2; ++i) {
        const int n = (tc0 + i) * 16 + r;
#pragma unroll
        for (int m = 0; m < 3; ++m) {
          bfrag b0 = *(const bfrag*)&wt[m][lad(n, g * 8)];
          bfrag b1 = *(const bfrag*)&wt[m][lad(n, 32 + g * 8)];
          acc[m][i] = __builtin_amdgcn_mfma_f32_16x16x32_bf16(a0, b0, acc[m][i], 0, 0, 0);
          acc[m][i] = __builtin_amdgcn_mfma_f32_16x16x32_bf16(a1, b1, acc[m][i], 0, 0, 0);
        }
      }
#pragma unroll
      for (int i = 0; i < 2; ++i) {
        const int col = (tc0 + i) * 16 + r;
        const float bq_ = bias_s[0][col], bk_ = bias_s[1][col];
#pragma unroll
        for (int j = 0; j < 4; ++j) {
          const int row = tr * 16 + g * 4 + j;
          const int ad = lad(row, col);
          Q[ad] = f2bf((acc[0][i][j] + bq_) * ATT_SCALE);
          R[ad] = f2bf(acc[1][i][j] + bk_);
        }
      }
      __syncthreads();                                     // bar B (P reads done)
#pragma unroll
      for (int i = 0; i < 2; ++i) {
        const int hd = (tc0 + i) * 16 + r;
        const float bv_ = bias_s[2][hd];
        const int graph = tr >> 1;
        const int tgrp = (tr & 1) * 2 + (g >> 1);
        unsigned p0 = cvt_pk(acc[2][i][0] + bv_, acc[2][i][1] + bv_);
        unsigned p1 = cvt_pk(acc[2][i][2] + bv_, acc[2][i][3] + bv_);
        const int ad = graph * 2048 + hd * 32 + ((tgrp ^ (hd & 3)) * 8) + (g & 1) * 4;
        *(unsigned*)&P[ad] = p0;
        *(unsigned*)&P[ad + 2] = p1;
      }
    }
    __syncthreads();                                       // bar C

    // ---- ph3: attention on MFMA (S^T = K Q^T; softmax lane-local; PV) ----
    {
      const int gidx2 = giter + gW;
#pragma unroll
      for (int u = 0; u < 2; ++u) {
        const int h = hb + u;
        bfrag kf0 = {0,0,0,0,0,0,0,0}, kf1 = kf0;
        if (g == 0) {
          kf0 = *(const bfrag*)&R[lad(gW * 32 + r, h * 8)];
          kf1 = *(const bfrag*)&R[lad(gW * 32 + 16 + r, h * 8)];
        }
#pragma unroll
        for (int st = 0; st < 2; ++st) {
          const int sL = st * 16 + r;
          bfrag qf = {0,0,0,0,0,0,0,0};
          if (g == 0) qf = *(const bfrag*)&Q[lad(gW * 32 + sL, h * 8)];
          f32x4 sc0 = zero4, sc1 = zero4;
          sc0 = __builtin_amdgcn_mfma_f32_16x16x32_bf16(kf0, qf, sc0, 0, 0, 0);
          sc1 = __builtin_amdgcn_mfma_f32_16x16x32_bf16(kf1, qf, sc1, 0, 0, 0);
          f32x4 wb0 = zero4, wb1 = zero4;
          if (batch_s[sL] == gidx2) {
            wb0 = *(const f32x4*)&W[(h * 32 + sL) * 32 + 4 * g];
            wb1 = *(const f32x4*)&W[(h * 32 + sL) * 32 + 16 + 4 * g];
          }
          float v0[4], v1[4];
#pragma unroll
          for (int j = 0; j < 4; ++j) { v0[j] = sc0[j] + wb0[j]; v1[j] = sc1[j] + wb1[j]; }
          float mx = fmaxf(fmaxf(fmaxf(v0[0], v0[1]), fmaxf(v0[2], v0[3])),
                           fmaxf(fmaxf(v1[0], v1[1]), fmaxf(v1[2], v1[3])));
          mx = fmaxf(mx, __shfl_xor(mx, 16));
          mx = fmaxf(mx, __shfl_xor(mx, 32));
          float e0[4], e1[4], ssum = 0.f;
#pragma unroll
          for (int j = 0; j < 4; ++j) {
            e0[j] = __expf(v0[j] - mx); e1[j] = __expf(v1[j] - mx);
            ssum += e0[j] + e1[j];
          }
          ssum += __shfl_xor(ssum, 16);
          ssum += __shfl_xor(ssum, 32);
          const float inv = __builtin_amdgcn_rcpf(ssum);
          unsigned u0 = cvt_pk(e0[0], e0[1]), u1 = cvt_pk(e0[2], e0[3]);
          unsigned u2 = cvt_pk(e1[0], e1[1]), u3 = cvt_pk(e1[2], e1[3]);
          const int srcA = ((g & 1) * 2) * 16 + r, srcB = srcA + 16;
          unsigned A0 = (unsigned)__shfl((int)u0, srcA);
          unsigned A2 = (unsigned)__shfl((int)u2, srcA);
          unsigned B0 = (unsigned)__shfl((int)u1, srcA);
          unsigned B2 = (unsigned)__shfl((int)u3, srcA);
          unsigned C0 = (unsigned)__shfl((int)u0, srcB);
          unsigned C2 = (unsigned)__shfl((int)u2, srcB);
          unsigned D0 = (unsigned)__shfl((int)u1, srcB);
          unsigned D2 = (unsigned)__shfl((int)u3, srcB);
          const bool hi = (g >> 1);
          uint4 bw;
          bw.x = hi ? A2 : A0;
          bw.y = hi ? B2 : B0;
          bw.z = hi ? C2 : C0;
          bw.w = hi ? D2 : D0;
          bfrag pb = *(bfrag*)&bw;
          bfrag vf = {0,0,0,0,0,0,0,0};
          if (r < 8) {
            const int hd = h * 8 + r;
            vf = *(const bfrag*)&P[gW * 2048 + hd * 32 + ((g ^ (hd & 3)) * 8)];
          }
          f32x4 o = zero4;
          o = __builtin_amdgcn_mfma_f32_16x16x32_bf16(vf, pb, o, 0, 0, 0);
          if (g < 2) {
            unsigned w0 = cvt_pk(o[0] * inv, o[1] * inv);
            unsigned w1 = cvt_pk(o[2] * inv, o[3] * inv);
            const int row = gW * 32 + sL;
            const int ad = lad(row, h * 8) + g * 4;
            *(unsigned*)&Q[ad] = w0;
            *(unsigned*)&Q[ad + 2] = w1;
          }
        }
      }
    }
    __syncthreads();                                       // bar D

    // ---- ph4: out-proj + residual; x1 -> R (bf16) + rx regs (f32) ----
    f32x4 rx[2];
    {
      f32x4 acc[2] = {zero4, zero4};
      mm2(Q, wt[3], acc);
#pragma unroll
      for (int i = 0; i < 2; ++i) {
        const int col = (tc0 + i) * 16 + r;
        const float bb = bias_s[3][col];
#pragma unroll
        for (int j = 0; j < 4; ++j) {
          const int row = tr * 16 + g * 4 + j;
          const float xv = x[((long)(giter * 32 + row)) * 64 + col];
          const float v = acc[i][j] + bb + xv;
          rx[i][j] = v;
          R[lad(row, col)] = f2bf(v);
        }
      }
    }
    __syncthreads();                                       // bar E

    // ---- ph5: LN2(x1) -> P ----
    {
      bfrag xv8 = *(const bfrag*)&R[lad(s8, c8)];
      float zv[8];
#pragma unroll
      for (int i = 0; i < 8; ++i) zv[i] = bf2f(xv8[i]);
      float sum = 0.f;
#pragma unroll
      for (int i = 0; i < 8; ++i) sum += zv[i];
      sum += __shfl_xor(sum, 1); sum += __shfl_xor(sum, 2); sum += __shfl_xor(sum, 4);
      const float m = sum * (1.f / 64.f);
      float sq = 0.f;
#pragma unroll
      for (int i = 0; i < 8; ++i) { float dd = zv[i] - m; sq += dd * dd; }
      sq += __shfl_xor(sq, 1); sq += __shfl_xor(sq, 2); sq += __shfl_xor(sq, 4);
      const float rs = rsqrtf(sq * (1.f / 64.f) + LN_EPS);
      bfrag zb;
#pragma unroll
      for (int i = 0; i < 8; ++i)
        zb[i] = f2bf((zv[i] - m) * rs * bias_s[8][c8 + i] + bias_s[9][c8 + i]);
      *(bfrag*)&P[lad(s8, c8)] = zb;
    }
    __syncthreads();                                       // bar F

    // ---- ph6: FFN1 + tanh-form GELU -> Q ----
    {
      f32x4 acc[2] = {zero4, zero4};
      mm2(P, wt[4], acc);
#pragma unroll
      for (int i = 0; i < 2; ++i) {
        const int col = (tc0 + i) * 16 + r;
        const float bb = bias_s[4][col];
#pragma unroll
        for (int j = 0; j < 4; ++j) {
          const int row = tr * 16 + g * 4 + j;
          const float u_ = acc[i][j] + bb;
          const float z = -1.5957691216f * (u_ + 0.044715f * u_ * u_ * u_);
          Q[lad(row, col)] = f2bf(u_ * __builtin_amdgcn_rcpf(1.f + __expf(z)));
        }
      }
    }
    __syncthreads();                                       // bar G

    // ---- ph7: FFN2 + residual -> out ----
    {
      f32x4 acc[2] = {zero4, zero4};
      mm2(Q, wt[5], acc);
#pragma unroll
      for (int i = 0; i < 2; ++i) {
        const int col = (tc0 + i) * 16 + r;
        const float bb = bias_s[5][col];
#pragma unroll
        for (int j = 0; j < 4; ++j) {
          const int row = tr * 16 + g * 4 + j;
          out[((long)(giter * 32 + row)) * 64 + col] = acc[i][j] + bb + rx[i][j];
        }
      }
    }
  }
}

extern "C" void kernel_launch(void* const* d_in, const int* in_sizes, int n_in,
                              void* d_out, int out_size, void* d_ws, size_t ws_size,
                              hipStream_t stream) {
  (void)in_sizes; (void)n_in; (void)out_size; (void)ws_size;
  cfp x         = (cfp)d_in[0];
  cfp edge_attr = (cfp)d_in[1];
  const int* edge_index = (const int*)d_in[2];
  const int* batch      = (const int*)d_in[3];
  cfp wq = (cfp)d_in[4];  cfp bq = (cfp)d_in[5];
  cfp wk = (cfp)d_in[6];  cfp bk = (cfp)d_in[7];
  cfp wv = (cfp)d_in[8];  cfp bv = (cfp)d_in[9];
  cfp we = (cfp)d_in[10]; cfp be = (cfp)d_in[11];
  cfp wo = (cfp)d_in[12]; cfp bo = (cfp)d_in[13];
  cfp ln1g = (cfp)d_in[14]; cfp ln1b = (cfp)d_in[15];
  cfp ln2g = (cfp)d_in[16]; cfp ln2b = (cfp)d_in[17];
  cfp w1 = (cfp)d_in[18]; cfp bf1 = (cfp)d_in[19];
  cfp w2 = (cfp)d_in[20]; cfp bf2 = (cfp)d_in[21];
  float* out = (float*)d_out;
  float* W = (float*)d_ws;        // NH*S*S floats = 32 KB
  float* Wpart = (float*)d_out;   // scratch: 8 MB of d_out, fully overwritten
                                  // later by the encoder's out writes

  edge_partial_kernel<<<EB, 256, 0, stream>>>(edge_attr, edge_index, we, be, Wpart);
  edge_reduce_kernel<<<64, 256, 0, stream>>>(Wpart, W);
  encoder_kernel<<<NB / GPB, 512, 0, stream>>>(x, batch,
      wq, bq, wk, bk, wv, bv, wo, bo,
      ln1g, ln1b, ln2g, ln2b, w1, bf1, w2, bf2, W, out);
}